// Round 6
// baseline (292.410 us; speedup 1.0000x reference)
//
#include <hip/hip_runtime.h>
#include <hip/hip_bf16.h>

// ---------------------------------------------------------------- K0: init
// Mt[16][8]: Mt[k][h] = (W_edge_att @ W_edge)[h][k]   (transposed for LDS)
// G[64][128]: G[h*8+k][i] = sum_d W[(h*8+d)*128+i] * W_att[k*8+d]
// Also: probe edge_index for int64 layout (odd int32 words all zero).
__global__ __launch_bounds__(256) void init_kernel(
        const float* __restrict__ W, const float* __restrict__ W_edge,
        const float* __restrict__ W_edge_att, const float* __restrict__ W_att,
        const int* __restrict__ ei,
        float* __restrict__ G, float* __restrict__ Mt,
        float* __restrict__ sumh, int* __restrict__ flags) {
    int tid = threadIdx.x;
    if (tid < 128) {
        int h = tid >> 4, k = tid & 15;
        float acc = 0.f;
        for (int j = 0; j < 64; ++j)
            acc += W_edge_att[h * 64 + j] * W_edge[j * 16 + k];
        Mt[k * 8 + h] = acc;
    }
    for (int idx = tid; idx < 64 * 128; idx += 256) {
        int l = idx >> 7, i = idx & 127;
        int h = l >> 3, k = l & 7;
        float acc = 0.f;
#pragma unroll
        for (int d = 0; d < 8; ++d)
            acc += W[(h * 8 + d) * 128 + i] * W_att[k * 8 + d];
        G[idx] = acc;
    }
    if (tid < 8) sumh[tid] = 0.f;
    if (tid == 0) {
        int zc = 0;
        for (int i = 1; i < 128; i += 2) zc += (ei[i] == 0);
        flags[0] = (zc >= 60) ? 1 : 0;
    }
}

// ---------------------------------------------------------------- K1: g = x @ G.T  (+ zero S)
// 256-row x 64-col tile per 256-thread block; 8 rows x 8 cols (64 acc) per lane.
// Per 4-wide K-window: 16 ds_read_b128 per 256 FMA = 2 FLOP/LDS-byte (vs 0.9 before).
// Row interleave rg+32r (sx stride 36) and col interleave cg+8c (sG stride 132)
// give conflict-free banks (4*rg / 4*cg patterns).
#define GK_ROWS 256
__global__ __launch_bounds__(256) void g_kernel(
        const float* __restrict__ x, const float* __restrict__ G,
        float* __restrict__ g, float* __restrict__ S, int N) {
    __shared__ float sG[64 * 132];    // 33.8 KB
    __shared__ float sx[256 * 36];    // 36.9 KB: 32-float K-chunk, stride 36
    int tid = threadIdx.x;
    int nbase = blockIdx.x * GK_ROWS;
    for (int f4 = tid; f4 < 2048; f4 += 256) {          // stage G once
        int l = f4 >> 5, i4 = f4 & 31;
        *(float4*)&sG[l * 132 + i4 * 4] = ((const float4*)G)[f4];
    }
    int rg = tid >> 3;       // 0..31
    int cg = tid & 7;        // 0..7
    float acc[8][8];
#pragma unroll
    for (int r = 0; r < 8; ++r)
#pragma unroll
        for (int c = 0; c < 8; ++c) acc[r][c] = 0.f;

    for (int k0 = 0; k0 < 128; k0 += 32) {
        __syncthreads();     // previous-iter readers done (also orders sG stage)
        for (int f4 = tid; f4 < 2048; f4 += 256) {      // stage x chunk
            int row = f4 >> 3, i4 = f4 & 7;
            int n = nbase + row;
            float4 v = make_float4(0.f, 0.f, 0.f, 0.f);
            if (n < N) v = *(const float4*)(x + (size_t)n * 128 + k0 + i4 * 4);
            *(float4*)&sx[row * 36 + i4 * 4] = v;
        }
        __syncthreads();
#pragma unroll
        for (int w = 0; w < 8; ++w) {
            float4 xv[8], gv[8];
#pragma unroll
            for (int r = 0; r < 8; ++r)
                xv[r] = *(const float4*)&sx[(rg + 32 * r) * 36 + w * 4];
#pragma unroll
            for (int c = 0; c < 8; ++c)
                gv[c] = *(const float4*)&sG[(cg + 8 * c) * 132 + k0 + w * 4];
#pragma unroll
            for (int r = 0; r < 8; ++r)
#pragma unroll
                for (int c = 0; c < 8; ++c)
                    acc[r][c] += xv[r].x * gv[c].x + xv[r].y * gv[c].y
                               + xv[r].z * gv[c].z + xv[r].w * gv[c].w;
        }
    }
#pragma unroll
    for (int r = 0; r < 8; ++r) {
        int n = nbase + rg + 32 * r;
        if (n < N) {
#pragma unroll
            for (int c = 0; c < 8; ++c)
                g[(size_t)n * 64 + cg + 8 * c] = acc[r][c];
        }
    }
    for (int idx = tid; idx < GK_ROWS * 8; idx += 256) { // zero S (ws is poisoned)
        int n = nbase + (idx >> 3);
        if (n < N) S[(size_t)n * 8 + (idx & 7)] = 0.f;
    }
}

// ---------------------------------------------------------------- K2: fused edge pass, (edge x head) per lane
#define EDGE_ITER 8
__global__ __launch_bounds__(256) void edge_kernel(
        const float* __restrict__ edge_attr, const int* __restrict__ ei,
        const float* __restrict__ Mt, const float* __restrict__ g,
        float* __restrict__ S, float* __restrict__ sumh,
        const int* __restrict__ flags, int E) {
    __shared__ float sMt[128];        // Mt[k][h]
    __shared__ float wsum[4][8];
    int tid = threadIdx.x;
    if (tid < 128) sMt[tid] = Mt[tid];
    __syncthreads();
    int idx64 = flags[0];
    int h = tid & 7;                  // head
    int grp = tid >> 3;               // 32 groups per block
    int ebase = blockIdx.x * (32 * EDGE_ITER);

    int sIdx[EDGE_ITER], dIdx[EDGE_ITER];
    if (idx64) {
        const long long* ei64 = (const long long*)ei;
#pragma unroll
        for (int it = 0; it < EDGE_ITER; ++it) {
            int e = ebase + it * 32 + grp;
            sIdx[it] = (e < E) ? (int)ei64[e] : 0;
            dIdx[it] = (e < E) ? (int)ei64[(size_t)E + e] : 0;
        }
    } else {
#pragma unroll
        for (int it = 0; it < EDGE_ITER; ++it) {
            int e = ebase + it * 32 + grp;
            sIdx[it] = (e < E) ? ei[e] : 0;
            dIdx[it] = (e < E) ? ei[(size_t)E + e] : 0;
        }
    }

    float wacc = 0.f;
#pragma unroll
    for (int it = 0; it < EDGE_ITER; ++it) {
        int e = ebase + it * 32 + grp;
        if (e < E) {
            const float4* p = (const float4*)(edge_attr + (size_t)e * 16);
            const float4* gs = (const float4*)(g + (size_t)sIdx[it] * 64 + h * 8);
            const float4* gd = (const float4*)(g + (size_t)dIdx[it] * 64 + h * 8);
            float4 a0 = gs[0], a1 = gs[1];
            float4 b0 = gd[0], b1 = gd[1];
            float4 v0 = p[0], v1 = p[1], v2 = p[2], v3 = p[3];
            float ea =
                sMt[0*8+h]*v0.x + sMt[1*8+h]*v0.y + sMt[2*8+h]*v0.z + sMt[3*8+h]*v0.w +
                sMt[4*8+h]*v1.x + sMt[5*8+h]*v1.y + sMt[6*8+h]*v1.z + sMt[7*8+h]*v1.w +
                sMt[8*8+h]*v2.x + sMt[9*8+h]*v2.y + sMt[10*8+h]*v2.z + sMt[11*8+h]*v2.w +
                sMt[12*8+h]*v3.x + sMt[13*8+h]*v3.y + sMt[14*8+h]*v3.z + sMt[15*8+h]*v3.w;
            float dot = a0.x * b0.x + a0.y * b0.y + a0.z * b0.z + a0.w * b0.w
                      + a1.x * b1.x + a1.y * b1.y + a1.z * b1.z + a1.w * b1.w;
            float t = dot + 8.f * ea;                  // edge_term = ea * D
            t = (t > 0.f) ? t : 0.2f * t;              // leaky_relu(0.2)
            float w = expf(t);
            unsafeAtomicAdd(S + (size_t)dIdx[it] * 8 + h, w);
            wacc += w;
        }
    }
    wacc += __shfl_xor(wacc, 8, 64);
    wacc += __shfl_xor(wacc, 16, 64);
    wacc += __shfl_xor(wacc, 32, 64);
    int wave = tid >> 6, lane = tid & 63;
    if (lane < 8) wsum[wave][lane] = wacc;
    __syncthreads();
    if (tid < 8)
        unsafeAtomicAdd(&sumh[tid], wsum[0][tid] + wsum[1][tid] + wsum[2][tid] + wsum[3][tid]);
}

// ---------------------------------------------------------------- K3: out = relu(((g .* S_broadcast) / sum_h) @ W_out.T)
__global__ __launch_bounds__(256) void out_kernel(
        const float* __restrict__ g, const float* __restrict__ S,
        const float* __restrict__ W_out, const float* __restrict__ sumh,
        float* __restrict__ out, int N) {
    __shared__ float sWo[8 * 68];
    __shared__ float sAgg[32 * 68];
    __shared__ float sSum[8];
    int tid = threadIdx.x;
    if (tid < 8) sSum[tid] = sumh[tid];
    __syncthreads();
    for (int idx = tid; idx < 512; idx += 256) {
        int k = idx >> 6, j = idx & 63;
        sWo[k * 68 + j] = W_out[idx] / sSum[j >> 3];   // fold softmax denom
    }
    int nbase = blockIdx.x * 32;
    for (int f4 = tid; f4 < 512; f4 += 256) {          // 32 rows x 16 float4
        int nl = f4 >> 4, j4 = f4 & 15;
        int n = nbase + nl;
        float4 v = make_float4(0.f, 0.f, 0.f, 0.f);
        if (n < N) {
            float sv = S[(size_t)n * 8 + (j4 >> 1)];
            float4 gv = ((const float4*)(g + (size_t)n * 64))[j4];
            v = make_float4(gv.x * sv, gv.y * sv, gv.z * sv, gv.w * sv);
        }
        *(float4*)&sAgg[nl * 68 + j4 * 4] = v;
    }
    __syncthreads();
    int nl = tid >> 3, k = tid & 7;
    int n = nbase + nl;
    float acc = 0.f;
#pragma unroll
    for (int j = 0; j < 64; j += 4) {
        float4 av = *(const float4*)&sAgg[nl * 68 + j];
        float4 wv = *(const float4*)&sWo[k * 68 + j];
        acc += av.x * wv.x + av.y * wv.y + av.z * wv.z + av.w * wv.w;
    }
    if (n < N)
        out[(size_t)n * 8 + k] = (acc > 0.f) ? acc : 0.f;
}

extern "C" void kernel_launch(void* const* d_in, const int* in_sizes, int n_in,
                              void* d_out, int out_size, void* d_ws, size_t ws_size,
                              hipStream_t stream) {
    const float* x          = (const float*)d_in[0];
    const float* edge_attr  = (const float*)d_in[1];
    const float* W          = (const float*)d_in[2];
    const float* W_edge     = (const float*)d_in[3];
    const float* W_edge_att = (const float*)d_in[4];
    const float* W_att      = (const float*)d_in[5];
    const float* W_out      = (const float*)d_in[6];
    const int*   ei         = (const int*)d_in[7];
    float* out = (float*)d_out;

    int N = in_sizes[0] / 128;   // 50000
    int E = in_sizes[1] / 16;    // 800000

    float* ws    = (float*)d_ws;
    float* G     = ws;                           // 8192
    float* Mt    = ws + 8192;                    // 128
    float* sumh  = ws + 8320;                    // 8
    int*   flags = (int*)(ws + 8328);            // 1
    float* g     = ws + 8448;                    // N*64
    float* S     = g + (size_t)N * 64;           // N*8
    // total ~14.4 MB of ws

    hipLaunchKernelGGL(init_kernel, dim3(1), dim3(256), 0, stream,
                       W, W_edge, W_edge_att, W_att, ei, G, Mt, sumh, flags);
    hipLaunchKernelGGL(g_kernel, dim3((N + GK_ROWS - 1) / GK_ROWS), dim3(256), 0, stream,
                       x, G, g, S, N);
    int epb = 32 * EDGE_ITER;   // 256 edges per block
    hipLaunchKernelGGL(edge_kernel, dim3((E + epb - 1) / epb), dim3(256), 0, stream,
                       edge_attr, ei, Mt, g, S, sumh, flags, E);
    hipLaunchKernelGGL(out_kernel, dim3((N + 31) / 32), dim3(256), 0, stream,
                       g, S, W_out, sumh, out, N);
}

// Round 7
// 249.326 us; speedup vs baseline: 1.1728x; 1.1728x over previous
//
#include <hip/hip_runtime.h>
#include <hip/hip_bf16.h>

typedef float f4v __attribute__((ext_vector_type(4)));

__device__ __forceinline__ float4 ntload4(const float* p) {
    f4v v = __builtin_nontemporal_load((const f4v*)p);
    return make_float4(v.x, v.y, v.z, v.w);
}

// ---------------------------------------------------------------- K0: init
// Mt[16][8]: Mt[k][h] = (W_edge_att @ W_edge)[h][k]   (transposed for LDS)
// G[64][128]: G[h*8+k][i] = sum_d W[(h*8+d)*128+i] * W_att[k*8+d]
// Also: probe edge_index for int64 layout (odd int32 words all zero).
__global__ __launch_bounds__(256) void init_kernel(
        const float* __restrict__ W, const float* __restrict__ W_edge,
        const float* __restrict__ W_edge_att, const float* __restrict__ W_att,
        const int* __restrict__ ei,
        float* __restrict__ G, float* __restrict__ Mt,
        float* __restrict__ sumh, int* __restrict__ flags) {
    int tid = threadIdx.x;
    if (tid < 128) {
        int h = tid >> 4, k = tid & 15;
        float acc = 0.f;
        for (int j = 0; j < 64; ++j)
            acc += W_edge_att[h * 64 + j] * W_edge[j * 16 + k];
        Mt[k * 8 + h] = acc;
    }
    for (int idx = tid; idx < 64 * 128; idx += 256) {
        int l = idx >> 7, i = idx & 127;
        int h = l >> 3, k = l & 7;
        float acc = 0.f;
#pragma unroll
        for (int d = 0; d < 8; ++d)
            acc += W[(h * 8 + d) * 128 + i] * W_att[k * 8 + d];
        G[idx] = acc;
    }
    if (tid < 8) sumh[tid] = 0.f;
    if (tid == 0) {
        int zc = 0;
        for (int i = 1; i < 128; i += 2) zc += (ei[i] == 0);
        flags[0] = (zc >= 60) ? 1 : 0;
    }
}

// ---------------------------------------------------------------- K1: g = x @ G.T  (+ zero S)
// 128-row x 64-col tile, 256 threads; lane computes 4 rows x 8 cols (32 acc).
// VGPR ~110 (acc 32 + gv 32 + xv 16) -- no spill (R6's 8x8 tile spilled at 256).
// Banks: rows rg+8r with sx stride 36 -> lane bank stride 4 (conflict-free);
// cols cg+8c with sG stride 132 -> bank stride 4 (conflict-free).
#define GT_ROWS 128
__global__ __launch_bounds__(256) void g_kernel(
        const float* __restrict__ x, const float* __restrict__ G,
        float* __restrict__ g, float* __restrict__ S, int N) {
    __shared__ float sG[64 * 132];   // 33.8 KB
    __shared__ float sx[128 * 36];   // 18.4 KB (32-float K-chunk)
    int tid = threadIdx.x;
    int nbase = blockIdx.x * GT_ROWS;
    for (int f4 = tid; f4 < 2048; f4 += 256) {          // stage G once
        int l = f4 >> 5, i4 = f4 & 31;
        *(float4*)&sG[l * 132 + i4 * 4] = ((const float4*)G)[f4];
    }
    int lane = tid & 63, wave = tid >> 6;
    int rg = lane >> 3;              // 0..7
    int cg = lane & 7;               // 0..7
    int rbase = wave * 32 + rg;      // rows rbase + 8*r, r=0..3
    float acc[4][8];
#pragma unroll
    for (int r = 0; r < 4; ++r)
#pragma unroll
        for (int c = 0; c < 8; ++c) acc[r][c] = 0.f;

    for (int k0 = 0; k0 < 128; k0 += 32) {
        __syncthreads();             // readers of previous chunk done (orders sG too)
        for (int f4 = tid; f4 < 1024; f4 += 256) {      // stage x K-chunk
            int row = f4 >> 3, i4 = f4 & 7;
            int n = nbase + row;
            float4 v = make_float4(0.f, 0.f, 0.f, 0.f);
            if (n < N) v = *(const float4*)(x + (size_t)n * 128 + k0 + i4 * 4);
            *(float4*)&sx[row * 36 + i4 * 4] = v;
        }
        __syncthreads();
#pragma unroll
        for (int w = 0; w < 8; ++w) {
            float4 gv[8], xv[4];
#pragma unroll
            for (int c = 0; c < 8; ++c)
                gv[c] = *(const float4*)&sG[(cg + 8 * c) * 132 + k0 + w * 4];
#pragma unroll
            for (int r = 0; r < 4; ++r)
                xv[r] = *(const float4*)&sx[(rbase + 8 * r) * 36 + w * 4];
#pragma unroll
            for (int r = 0; r < 4; ++r)
#pragma unroll
                for (int c = 0; c < 8; ++c)
                    acc[r][c] += xv[r].x * gv[c].x + xv[r].y * gv[c].y
                               + xv[r].z * gv[c].z + xv[r].w * gv[c].w;
        }
    }
#pragma unroll
    for (int r = 0; r < 4; ++r) {
        int n = nbase + rbase + 8 * r;
        if (n < N) {
#pragma unroll
            for (int c = 0; c < 8; ++c)
                g[(size_t)n * 64 + cg + 8 * c] = acc[r][c];
        }
    }
    for (int idx = tid; idx < GT_ROWS * 8; idx += 256) { // zero S (ws is poisoned)
        int n = nbase + (idx >> 3);
        if (n < N) S[(size_t)n * 8 + (idx & 7)] = 0.f;
    }
}

// ---------------------------------------------------------------- K2: fused edge pass, (edge x head) per lane
// edge_attr / ei are streamed once -> non-temporal loads, keep L2 for the g table.
#define EDGE_ITER 8
__global__ __launch_bounds__(256) void edge_kernel(
        const float* __restrict__ edge_attr, const int* __restrict__ ei,
        const float* __restrict__ Mt, const float* __restrict__ g,
        float* __restrict__ S, float* __restrict__ sumh,
        const int* __restrict__ flags, int E) {
    __shared__ float sMt[128];        // Mt[k][h]
    __shared__ float wsum[4][8];
    int tid = threadIdx.x;
    if (tid < 128) sMt[tid] = Mt[tid];
    __syncthreads();
    int idx64 = flags[0];
    int h = tid & 7;                  // head
    int grp = tid >> 3;               // 32 groups per block
    int ebase = blockIdx.x * (32 * EDGE_ITER);

    int sIdx[EDGE_ITER], dIdx[EDGE_ITER];
    if (idx64) {
        const long long* ei64 = (const long long*)ei;
#pragma unroll
        for (int it = 0; it < EDGE_ITER; ++it) {
            int e = ebase + it * 32 + grp;
            sIdx[it] = (e < E) ? (int)__builtin_nontemporal_load(ei64 + e) : 0;
            dIdx[it] = (e < E) ? (int)__builtin_nontemporal_load(ei64 + (size_t)E + e) : 0;
        }
    } else {
#pragma unroll
        for (int it = 0; it < EDGE_ITER; ++it) {
            int e = ebase + it * 32 + grp;
            sIdx[it] = (e < E) ? __builtin_nontemporal_load(ei + e) : 0;
            dIdx[it] = (e < E) ? __builtin_nontemporal_load(ei + (size_t)E + e) : 0;
        }
    }

    float wacc = 0.f;
#pragma unroll
    for (int it = 0; it < EDGE_ITER; ++it) {
        int e = ebase + it * 32 + grp;
        if (e < E) {
            const float* p = edge_attr + (size_t)e * 16;
            const float4* gs = (const float4*)(g + (size_t)sIdx[it] * 64 + h * 8);
            const float4* gd = (const float4*)(g + (size_t)dIdx[it] * 64 + h * 8);
            float4 a0 = gs[0], a1 = gs[1];
            float4 b0 = gd[0], b1 = gd[1];
            float4 v0 = ntload4(p), v1 = ntload4(p + 4),
                   v2 = ntload4(p + 8), v3 = ntload4(p + 12);
            float ea =
                sMt[0*8+h]*v0.x + sMt[1*8+h]*v0.y + sMt[2*8+h]*v0.z + sMt[3*8+h]*v0.w +
                sMt[4*8+h]*v1.x + sMt[5*8+h]*v1.y + sMt[6*8+h]*v1.z + sMt[7*8+h]*v1.w +
                sMt[8*8+h]*v2.x + sMt[9*8+h]*v2.y + sMt[10*8+h]*v2.z + sMt[11*8+h]*v2.w +
                sMt[12*8+h]*v3.x + sMt[13*8+h]*v3.y + sMt[14*8+h]*v3.z + sMt[15*8+h]*v3.w;
            float dot = a0.x * b0.x + a0.y * b0.y + a0.z * b0.z + a0.w * b0.w
                      + a1.x * b1.x + a1.y * b1.y + a1.z * b1.z + a1.w * b1.w;
            float t = dot + 8.f * ea;                  // edge_term = ea * D
            t = (t > 0.f) ? t : 0.2f * t;              // leaky_relu(0.2)
            float w = expf(t);
            unsafeAtomicAdd(S + (size_t)dIdx[it] * 8 + h, w);
            wacc += w;
        }
    }
    wacc += __shfl_xor(wacc, 8, 64);
    wacc += __shfl_xor(wacc, 16, 64);
    wacc += __shfl_xor(wacc, 32, 64);
    int wave = tid >> 6, lane = tid & 63;
    if (lane < 8) wsum[wave][lane] = wacc;
    __syncthreads();
    if (tid < 8)
        unsafeAtomicAdd(&sumh[tid], wsum[0][tid] + wsum[1][tid] + wsum[2][tid] + wsum[3][tid]);
}

// ---------------------------------------------------------------- K3: out = relu(((g .* S_broadcast) / sum_h) @ W_out.T)
__global__ __launch_bounds__(256) void out_kernel(
        const float* __restrict__ g, const float* __restrict__ S,
        const float* __restrict__ W_out, const float* __restrict__ sumh,
        float* __restrict__ out, int N) {
    __shared__ float sWo[8 * 68];
    __shared__ float sAgg[32 * 68];
    __shared__ float sSum[8];
    int tid = threadIdx.x;
    if (tid < 8) sSum[tid] = sumh[tid];
    __syncthreads();
    for (int idx = tid; idx < 512; idx += 256) {
        int k = idx >> 6, j = idx & 63;
        sWo[k * 68 + j] = W_out[idx] / sSum[j >> 3];   // fold softmax denom
    }
    int nbase = blockIdx.x * 32;
    for (int f4 = tid; f4 < 512; f4 += 256) {          // 32 rows x 16 float4
        int nl = f4 >> 4, j4 = f4 & 15;
        int n = nbase + nl;
        float4 v = make_float4(0.f, 0.f, 0.f, 0.f);
        if (n < N) {
            float sv = S[(size_t)n * 8 + (j4 >> 1)];
            float4 gv = ((const float4*)(g + (size_t)n * 64))[j4];
            v = make_float4(gv.x * sv, gv.y * sv, gv.z * sv, gv.w * sv);
        }
        *(float4*)&sAgg[nl * 68 + j4 * 4] = v;
    }
    __syncthreads();
    int nl = tid >> 3, k = tid & 7;
    int n = nbase + nl;
    float acc = 0.f;
#pragma unroll
    for (int j = 0; j < 64; j += 4) {
        float4 av = *(const float4*)&sAgg[nl * 68 + j];
        float4 wv = *(const float4*)&sWo[k * 68 + j];
        acc += av.x * wv.x + av.y * wv.y + av.z * wv.z + av.w * wv.w;
    }
    if (n < N)
        out[(size_t)n * 8 + k] = (acc > 0.f) ? acc : 0.f;
}

extern "C" void kernel_launch(void* const* d_in, const int* in_sizes, int n_in,
                              void* d_out, int out_size, void* d_ws, size_t ws_size,
                              hipStream_t stream) {
    const float* x          = (const float*)d_in[0];
    const float* edge_attr  = (const float*)d_in[1];
    const float* W          = (const float*)d_in[2];
    const float* W_edge     = (const float*)d_in[3];
    const float* W_edge_att = (const float*)d_in[4];
    const float* W_att      = (const float*)d_in[5];
    const float* W_out      = (const float*)d_in[6];
    const int*   ei         = (const int*)d_in[7];
    float* out = (float*)d_out;

    int N = in_sizes[0] / 128;   // 50000
    int E = in_sizes[1] / 16;    // 800000

    float* ws    = (float*)d_ws;
    float* G     = ws;                           // 8192
    float* Mt    = ws + 8192;                    // 128
    float* sumh  = ws + 8320;                    // 8
    int*   flags = (int*)(ws + 8328);            // 1
    float* g     = ws + 8448;                    // N*64
    float* S     = g + (size_t)N * 64;           // N*8
    // total ~14.4 MB of ws

    hipLaunchKernelGGL(init_kernel, dim3(1), dim3(256), 0, stream,
                       W, W_edge, W_edge_att, W_att, ei, G, Mt, sumh, flags);
    hipLaunchKernelGGL(g_kernel, dim3((N + GT_ROWS - 1) / GT_ROWS), dim3(256), 0, stream,
                       x, G, g, S, N);
    int epb = 32 * EDGE_ITER;   // 256 edges per block
    hipLaunchKernelGGL(edge_kernel, dim3((E + epb - 1) / epb), dim3(256), 0, stream,
                       edge_attr, ei, Mt, g, S, sumh, flags, E);
    hipLaunchKernelGGL(out_kernel, dim3((N + 31) / 32), dim3(256), 0, stream,
                       g, S, W_out, sumh, out, N);
}

// Round 8
// 232.080 us; speedup vs baseline: 1.2600x; 1.0743x over previous
//
#include <hip/hip_runtime.h>
#include <hip/hip_fp16.h>

// ---------------------------------------------------------------- K0: init (33 blocks)
// blocks 0..31: G[64][128], 2 rows each: G[h*8+k][i] = sum_d W[(h*8+d)*128+i]*W_att[k*8+d]
// block 32: Mt[16][8] = (W_edge_att @ W_edge)^T, sumh=0, int64-probe flag.
__global__ __launch_bounds__(256) void init_kernel(
        const float* __restrict__ W, const float* __restrict__ W_edge,
        const float* __restrict__ W_edge_att, const float* __restrict__ W_att,
        const int* __restrict__ ei,
        float* __restrict__ G, float* __restrict__ Mt,
        float* __restrict__ sumh, int* __restrict__ flags) {
    int tid = threadIdx.x;
    int b = blockIdx.x;
    if (b < 32) {
        int l = b * 2 + (tid >> 7);      // 0..63
        int i = tid & 127;
        int h = l >> 3, k = l & 7;
        float acc = 0.f;
#pragma unroll
        for (int d = 0; d < 8; ++d)
            acc += W[(h * 8 + d) * 128 + i] * W_att[k * 8 + d];
        G[l * 128 + i] = acc;
    } else {
        if (tid < 128) {
            int h = tid >> 4, k = tid & 15;
            float acc = 0.f;
#pragma unroll 8
            for (int j = 0; j < 64; ++j)
                acc += W_edge_att[h * 64 + j] * W_edge[j * 16 + k];
            Mt[k * 8 + h] = acc;
        }
        if (tid < 8) sumh[tid] = 0.f;
        if (tid == 0) {
            int zc = 0;
            for (int i = 1; i < 128; i += 2) zc += (ei[i] == 0);
            flags[0] = (zc >= 60) ? 1 : 0;
        }
    }
}

// ---------------------------------------------------------------- K1: g = x @ G.T (+ g16 fp16 copy + zero S)
// 128-row x 64-col tile, lane = 4 rows x 8 cols (32 acc, ~110 VGPR, no spill).
// Epilogue transposes acc through LDS to emit packed fp16 rows for the edge gathers.
#define GT_ROWS 128
__global__ __launch_bounds__(256) void g_kernel(
        const float* __restrict__ x, const float* __restrict__ G,
        float* __restrict__ g, __half* __restrict__ g16,
        float* __restrict__ S, int N) {
    __shared__ float smem[13056];    // 52.2 KB: sG[64*132] | sx[128*36]; epilogue reuses as 128*68
    float* sG = smem;
    float* sx = smem + 8448;
    int tid = threadIdx.x;
    int nbase = blockIdx.x * GT_ROWS;
    for (int f4 = tid; f4 < 2048; f4 += 256) {          // stage G once
        int l = f4 >> 5, i4 = f4 & 31;
        *(float4*)&sG[l * 132 + i4 * 4] = ((const float4*)G)[f4];
    }
    int lane = tid & 63, wave = tid >> 6;
    int rg = lane >> 3;              // 0..7
    int cg = lane & 7;               // 0..7
    int rbase = wave * 32 + rg;      // block-local rows rbase + 8*r
    float acc[4][8];
#pragma unroll
    for (int r = 0; r < 4; ++r)
#pragma unroll
        for (int c = 0; c < 8; ++c) acc[r][c] = 0.f;

    for (int k0 = 0; k0 < 128; k0 += 32) {
        __syncthreads();
        for (int f4 = tid; f4 < 1024; f4 += 256) {      // stage x K-chunk
            int row = f4 >> 3, i4 = f4 & 7;
            int n = nbase + row;
            float4 v = make_float4(0.f, 0.f, 0.f, 0.f);
            if (n < N) v = *(const float4*)(x + (size_t)n * 128 + k0 + i4 * 4);
            *(float4*)&sx[row * 36 + i4 * 4] = v;
        }
        __syncthreads();
#pragma unroll
        for (int w = 0; w < 8; ++w) {
            float4 gv[8], xv[4];
#pragma unroll
            for (int c = 0; c < 8; ++c)
                gv[c] = *(const float4*)&sG[(cg + 8 * c) * 132 + k0 + w * 4];
#pragma unroll
            for (int r = 0; r < 4; ++r)
                xv[r] = *(const float4*)&sx[(rbase + 8 * r) * 36 + w * 4];
#pragma unroll
            for (int r = 0; r < 4; ++r)
#pragma unroll
                for (int c = 0; c < 8; ++c)
                    acc[r][c] += xv[r].x * gv[c].x + xv[r].y * gv[c].y
                               + xv[r].z * gv[c].z + xv[r].w * gv[c].w;
        }
    }
    // fp32 g store straight from registers
#pragma unroll
    for (int r = 0; r < 4; ++r) {
        int n = nbase + rbase + 8 * r;
        if (n < N) {
#pragma unroll
            for (int c = 0; c < 8; ++c)
                g[(size_t)n * 64 + cg + 8 * c] = acc[r][c];
        }
    }
    // transpose via LDS -> packed fp16 rows (lane cols are stride-8, need contiguity)
    __syncthreads();
#pragma unroll
    for (int r = 0; r < 4; ++r)
#pragma unroll
        for (int c = 0; c < 8; ++c)
            smem[(rbase + 8 * r) * 68 + cg + 8 * c] = acc[r][c];
    __syncthreads();
    for (int u = tid; u < 1024; u += 256) {             // 128 rows x 8 uint4
        int row = u >> 3, q = u & 7;
        int n = nbase + row;
        if (n < N) {
            float4 f0 = *(const float4*)&smem[row * 68 + q * 8];
            float4 f1 = *(const float4*)&smem[row * 68 + q * 8 + 4];
            __half2 h0 = __floats2half2_rn(f0.x, f0.y);
            __half2 h1 = __floats2half2_rn(f0.z, f0.w);
            __half2 h2 = __floats2half2_rn(f1.x, f1.y);
            __half2 h3 = __floats2half2_rn(f1.z, f1.w);
            uint4 uv = make_uint4(*(unsigned*)&h0, *(unsigned*)&h1,
                                  *(unsigned*)&h2, *(unsigned*)&h3);
            ((uint4*)g16)[(size_t)n * 8 + q] = uv;
        }
    }
    for (int idx = tid; idx < GT_ROWS * 8; idx += 256) { // zero S (ws is poisoned)
        int n = nbase + (idx >> 3);
        if (n < N) S[(size_t)n * 8 + (idx & 7)] = 0.f;
    }
}

// ---------------------------------------------------------------- K2: fused edge pass, (edge x head) per lane
// fp16 gathers (one uint4 per row-half) + depth-2 register pipeline.
#define EDGE_ITER 8
__global__ __launch_bounds__(256) void edge_kernel(
        const float* __restrict__ edge_attr, const int* __restrict__ ei,
        const float* __restrict__ Mt, const __half* __restrict__ g16,
        float* __restrict__ S, float* __restrict__ sumh,
        const int* __restrict__ flags, int E) {
    __shared__ float sMt[128];        // Mt[k][h]
    __shared__ float wsum[4][8];
    int tid = threadIdx.x;
    if (tid < 128) sMt[tid] = Mt[tid];
    __syncthreads();
    int idx64 = flags[0];
    int h = tid & 7;                  // head
    int grp = tid >> 3;               // 32 groups per block
    int ebase = blockIdx.x * (32 * EDGE_ITER);

    int sIdx[EDGE_ITER], dIdx[EDGE_ITER];
    if (idx64) {
        const long long* ei64 = (const long long*)ei;
#pragma unroll
        for (int it = 0; it < EDGE_ITER; ++it) {
            int e = ebase + it * 32 + grp;
            sIdx[it] = (e < E) ? (int)ei64[e] : 0;
            dIdx[it] = (e < E) ? (int)ei64[(size_t)E + e] : 0;
        }
    } else {
#pragma unroll
        for (int it = 0; it < EDGE_ITER; ++it) {
            int e = ebase + it * 32 + grp;
            sIdx[it] = (e < E) ? ei[e] : 0;
            dIdx[it] = (e < E) ? ei[(size_t)E + e] : 0;
        }
    }

    float4 at[2][4];
    uint4 gsv[2], gdv[2];
    const uint4* g16v = (const uint4*)g16;
    // prefetch iteration 0
    {
        int e = ebase + grp;
        if (e < E) {
            const float4* p = (const float4*)(edge_attr + (size_t)e * 16);
            at[0][0] = p[0]; at[0][1] = p[1]; at[0][2] = p[2]; at[0][3] = p[3];
            gsv[0] = g16v[(size_t)sIdx[0] * 8 + h];
            gdv[0] = g16v[(size_t)dIdx[0] * 8 + h];
        }
    }
    float wacc = 0.f;
#pragma unroll
    for (int it = 0; it < EDGE_ITER; ++it) {
        int buf = it & 1;
        if (it + 1 < EDGE_ITER) {                 // issue next stage's loads
            int e2 = ebase + (it + 1) * 32 + grp;
            if (e2 < E) {
                const float4* p = (const float4*)(edge_attr + (size_t)e2 * 16);
                at[buf ^ 1][0] = p[0]; at[buf ^ 1][1] = p[1];
                at[buf ^ 1][2] = p[2]; at[buf ^ 1][3] = p[3];
                gsv[buf ^ 1] = g16v[(size_t)sIdx[it + 1] * 8 + h];
                gdv[buf ^ 1] = g16v[(size_t)dIdx[it + 1] * 8 + h];
            }
        }
        int e = ebase + it * 32 + grp;
        if (e < E) {
            float4 v0 = at[buf][0], v1 = at[buf][1], v2 = at[buf][2], v3 = at[buf][3];
            float ea =
                sMt[0*8+h]*v0.x + sMt[1*8+h]*v0.y + sMt[2*8+h]*v0.z + sMt[3*8+h]*v0.w +
                sMt[4*8+h]*v1.x + sMt[5*8+h]*v1.y + sMt[6*8+h]*v1.z + sMt[7*8+h]*v1.w +
                sMt[8*8+h]*v2.x + sMt[9*8+h]*v2.y + sMt[10*8+h]*v2.z + sMt[11*8+h]*v2.w +
                sMt[12*8+h]*v3.x + sMt[13*8+h]*v3.y + sMt[14*8+h]*v3.z + sMt[15*8+h]*v3.w;
            const __half2* a2 = (const __half2*)&gsv[buf];
            const __half2* b2 = (const __half2*)&gdv[buf];
            float dot = 0.f;
#pragma unroll
            for (int j = 0; j < 4; ++j) {
                float2 fa = __half22float2(a2[j]);
                float2 fb = __half22float2(b2[j]);
                dot += fa.x * fb.x + fa.y * fb.y;
            }
            float t = dot + 8.f * ea;                  // edge_term = ea * D
            t = (t > 0.f) ? t : 0.2f * t;              // leaky_relu(0.2)
            float w = expf(t);
            unsafeAtomicAdd(S + (size_t)dIdx[it] * 8 + h, w);
            wacc += w;
        }
    }
    wacc += __shfl_xor(wacc, 8, 64);
    wacc += __shfl_xor(wacc, 16, 64);
    wacc += __shfl_xor(wacc, 32, 64);
    int wave = tid >> 6, lane = tid & 63;
    if (lane < 8) wsum[wave][lane] = wacc;
    __syncthreads();
    if (tid < 8)
        unsafeAtomicAdd(&sumh[tid], wsum[0][tid] + wsum[1][tid] + wsum[2][tid] + wsum[3][tid]);
}

// ---------------------------------------------------------------- K3: out = relu(((g .* S_broadcast) / sum_h) @ W_out.T)
__global__ __launch_bounds__(256) void out_kernel(
        const float* __restrict__ g, const float* __restrict__ S,
        const float* __restrict__ W_out, const float* __restrict__ sumh,
        float* __restrict__ out, int N) {
    __shared__ float sWo[8 * 68];
    __shared__ float sAgg[32 * 68];
    __shared__ float sSum[8];
    int tid = threadIdx.x;
    if (tid < 8) sSum[tid] = sumh[tid];
    __syncthreads();
    for (int idx = tid; idx < 512; idx += 256) {
        int k = idx >> 6, j = idx & 63;
        sWo[k * 68 + j] = W_out[idx] / sSum[j >> 3];   // fold softmax denom
    }
    int nbase = blockIdx.x * 32;
    for (int f4 = tid; f4 < 512; f4 += 256) {          // 32 rows x 16 float4
        int nl = f4 >> 4, j4 = f4 & 15;
        int n = nbase + nl;
        float4 v = make_float4(0.f, 0.f, 0.f, 0.f);
        if (n < N) {
            float sv = S[(size_t)n * 8 + (j4 >> 1)];
            float4 gv = ((const float4*)(g + (size_t)n * 64))[j4];
            v = make_float4(gv.x * sv, gv.y * sv, gv.z * sv, gv.w * sv);
        }
        *(float4*)&sAgg[nl * 68 + j4 * 4] = v;
    }
    __syncthreads();
    int nl = tid >> 3, k = tid & 7;
    int n = nbase + nl;
    float acc = 0.f;
#pragma unroll
    for (int j = 0; j < 64; j += 4) {
        float4 av = *(const float4*)&sAgg[nl * 68 + j];
        float4 wv = *(const float4*)&sWo[k * 68 + j];
        acc += av.x * wv.x + av.y * wv.y + av.z * wv.z + av.w * wv.w;
    }
    if (n < N)
        out[(size_t)n * 8 + k] = (acc > 0.f) ? acc : 0.f;
}

extern "C" void kernel_launch(void* const* d_in, const int* in_sizes, int n_in,
                              void* d_out, int out_size, void* d_ws, size_t ws_size,
                              hipStream_t stream) {
    const float* x          = (const float*)d_in[0];
    const float* edge_attr  = (const float*)d_in[1];
    const float* W          = (const float*)d_in[2];
    const float* W_edge     = (const float*)d_in[3];
    const float* W_edge_att = (const float*)d_in[4];
    const float* W_att      = (const float*)d_in[5];
    const float* W_out      = (const float*)d_in[6];
    const int*   ei         = (const int*)d_in[7];
    float* out = (float*)d_out;

    int N = in_sizes[0] / 128;   // 50000
    int E = in_sizes[1] / 16;    // 800000

    float* ws    = (float*)d_ws;
    float* G     = ws;                           // 8192
    float* Mt    = ws + 8192;                    // 128
    float* sumh  = ws + 8320;                    // 8
    int*   flags = (int*)(ws + 8328);            // 1
    float* g     = ws + 8448;                    // N*64 fp32
    float* S     = g + (size_t)N * 64;           // N*8
    __half* g16  = (__half*)(S + (size_t)N * 8); // N*64 fp16 (16B-aligned)
    // total ~21 MB of ws

    hipLaunchKernelGGL(init_kernel, dim3(33), dim3(256), 0, stream,
                       W, W_edge, W_edge_att, W_att, ei, G, Mt, sumh, flags);
    hipLaunchKernelGGL(g_kernel, dim3((N + GT_ROWS - 1) / GT_ROWS), dim3(256), 0, stream,
                       x, G, g, g16, S, N);
    int epb = 32 * EDGE_ITER;   // 256 edges per block
    hipLaunchKernelGGL(edge_kernel, dim3((E + epb - 1) / epb), dim3(256), 0, stream,
                       edge_attr, ei, Mt, g16, S, sumh, flags, E);
    hipLaunchKernelGGL(out_kernel, dim3((N + 31) / 32), dim3(256), 0, stream,
                       g, S, W_out, sumh, out, N);
}